// Round 1
// baseline (5956.237 us; speedup 1.0000x reference)
//
#include <hip/hip_runtime.h>

// 3-layer sparse conv (ME-style gather-GEMM-scatter), fp32.
// Layout decisions:
//  - lane = map entry (pair): coalesced map reads, per-lane float4 row gather,
//    C_out accumulators in VGPRs, W wave-uniform -> s_load, fmac w/ SGPR operand.
//  - k=13 (center offset) of map1/map3 is the identity covering all output rows:
//    run dense with plain stores (no zero-init of y1 / d_out needed, b3 folded in).
//  - cross-k accumulation via native fp32 atomics (unsafeAtomicAdd).
//  - bias+ReLU fused into the next layer's gather.

#define TPB 256

__global__ void __launch_bounds__(TPB)
k_conv1_center(const float* __restrict__ x, const float* __restrict__ W1,
               float* __restrict__ y1, int n1) {
  int r = blockIdx.x * TPB + threadIdx.x;
  if (r >= n1) return;
  const float4* xr = (const float4*)(x + (size_t)r * 8);
  float4 a = xr[0], b = xr[1];
  float xv[8] = {a.x, a.y, a.z, a.w, b.x, b.y, b.z, b.w};
  const float* __restrict__ Wc = W1 + 13 * 512;  // 27 x 8 x 64, k=13
  float acc[64];
#pragma unroll
  for (int j = 0; j < 64; ++j) acc[j] = 0.f;
#pragma unroll
  for (int i = 0; i < 8; ++i) {
#pragma unroll
    for (int j = 0; j < 64; ++j)
      acc[j] = fmaf(xv[i], Wc[i * 64 + j], acc[j]);
  }
  float4* yr = (float4*)(y1 + (size_t)r * 64);
#pragma unroll
  for (int q = 0; q < 16; ++q)
    yr[q] = make_float4(acc[4*q], acc[4*q+1], acc[4*q+2], acc[4*q+3]);
}

__global__ void __launch_bounds__(TPB)
k_conv1_rest(const float* __restrict__ x, const float* __restrict__ W1,
             const int* __restrict__ min_, const int* __restrict__ mout_,
             float* __restrict__ y1, int L1, int n1) {
  int k = blockIdx.y;
  if (k >= 13) ++k;                       // skip center (done dense)
  const int* mi = min_ + (size_t)k * L1;
  const int* mo = mout_ + (size_t)k * L1;
  const float* __restrict__ Wk = W1 + (size_t)k * 512;
  int p = blockIdx.x * TPB + threadIdx.x;
  if (p >= L1) return;
  int out = mo[p];
  bool valid = out < n1;                  // pads point at dummy row n1
  if (__ballot(valid) == 0ull) return;    // pads are a contiguous tail
  int in = valid ? mi[p] : 0;
  const float4* xr = (const float4*)(x + (size_t)in * 8);
  float4 a = xr[0], b = xr[1];
  float xv[8] = {a.x, a.y, a.z, a.w, b.x, b.y, b.z, b.w};
  float acc[64];
#pragma unroll
  for (int j = 0; j < 64; ++j) acc[j] = 0.f;
#pragma unroll
  for (int i = 0; i < 8; ++i) {
#pragma unroll
    for (int j = 0; j < 64; ++j)
      acc[j] = fmaf(xv[i], Wk[i * 64 + j], acc[j]);
  }
  if (valid) {
    float* yr = y1 + (size_t)out * 64;
#pragma unroll
    for (int j = 0; j < 64; ++j) unsafeAtomicAdd(&yr[j], acc[j]);
  }
}

__global__ void __launch_bounds__(TPB)
k_conv2(const float* __restrict__ y1, const float* __restrict__ b1,
        const float* __restrict__ W2,
        const int* __restrict__ min_, const int* __restrict__ mout_,
        float* __restrict__ y2, int L2, int n2) {
  int k = blockIdx.y;                     // 0..7
  const int* mi = min_ + (size_t)k * L2;
  const int* mo = mout_ + (size_t)k * L2;
  const float* __restrict__ Wk = W2 + (size_t)k * 4096;  // 64 x 64
  int p = blockIdx.x * TPB + threadIdx.x;
  if (p >= L2) return;
  int out = mo[p];
  bool valid = out < n2;
  if (__ballot(valid) == 0ull) return;
  int in = valid ? mi[p] : 0;
  const float4* xr = (const float4*)(y1 + (size_t)in * 64);
  float acc[64];
#pragma unroll
  for (int j = 0; j < 64; ++j) acc[j] = 0.f;
#pragma unroll 4
  for (int c = 0; c < 16; ++c) {
    float4 xv = xr[c];
    // fused h1 = relu(conv1 + b1) at gather time (b1 wave-uniform)
    float h0 = fmaxf(xv.x + b1[4*c+0], 0.f);
    float h1 = fmaxf(xv.y + b1[4*c+1], 0.f);
    float h2 = fmaxf(xv.z + b1[4*c+2], 0.f);
    float h3 = fmaxf(xv.w + b1[4*c+3], 0.f);
#pragma unroll
    for (int j = 0; j < 64; ++j) {
      acc[j] = fmaf(h0, Wk[(4*c+0)*64 + j], acc[j]);
      acc[j] = fmaf(h1, Wk[(4*c+1)*64 + j], acc[j]);
      acc[j] = fmaf(h2, Wk[(4*c+2)*64 + j], acc[j]);
      acc[j] = fmaf(h3, Wk[(4*c+3)*64 + j], acc[j]);
    }
  }
  if (valid) {
    float* yr = y2 + (size_t)out * 64;
#pragma unroll
    for (int j = 0; j < 64; ++j) unsafeAtomicAdd(&yr[j], acc[j]);
  }
}

__global__ void __launch_bounds__(TPB)
k_conv3_center(const float* __restrict__ y2, const float* __restrict__ b2,
               const float* __restrict__ W3, const float* __restrict__ b3,
               float* __restrict__ out, int n2) {
  int r = blockIdx.x * TPB + threadIdx.x;
  if (r >= n2) return;
  const float4* xr = (const float4*)(y2 + (size_t)r * 64);
  const float* __restrict__ Wc = W3 + 13 * 512;  // 27 x 64 x 8, k=13
  float acc[8];
#pragma unroll
  for (int j = 0; j < 8; ++j) acc[j] = b3[j];    // fold bias via first-touch
#pragma unroll
  for (int c = 0; c < 16; ++c) {
    float4 xv = xr[c];
    float h[4];
    h[0] = fmaxf(xv.x + b2[4*c+0], 0.f);
    h[1] = fmaxf(xv.y + b2[4*c+1], 0.f);
    h[2] = fmaxf(xv.z + b2[4*c+2], 0.f);
    h[3] = fmaxf(xv.w + b2[4*c+3], 0.f);
#pragma unroll
    for (int u = 0; u < 4; ++u)
#pragma unroll
      for (int j = 0; j < 8; ++j)
        acc[j] = fmaf(h[u], Wc[(4*c+u)*8 + j], acc[j]);
  }
  float4* o = (float4*)(out + (size_t)r * 8);
  o[0] = make_float4(acc[0], acc[1], acc[2], acc[3]);
  o[1] = make_float4(acc[4], acc[5], acc[6], acc[7]);
}

__global__ void __launch_bounds__(TPB)
k_conv3_rest(const float* __restrict__ y2, const float* __restrict__ b2,
             const float* __restrict__ W3,
             const int* __restrict__ min_, const int* __restrict__ mout_,
             float* __restrict__ out, int L3, int n2) {
  int k = blockIdx.y;
  if (k >= 13) ++k;
  const int* mi = min_ + (size_t)k * L3;
  const int* mo = mout_ + (size_t)k * L3;
  const float* __restrict__ Wk = W3 + (size_t)k * 512;
  int p = blockIdx.x * TPB + threadIdx.x;
  if (p >= L3) return;
  int o_ = mo[p];
  bool valid = o_ < n2;
  if (__ballot(valid) == 0ull) return;
  int in = valid ? mi[p] : 0;
  const float4* xr = (const float4*)(y2 + (size_t)in * 64);
  float acc[8];
#pragma unroll
  for (int j = 0; j < 8; ++j) acc[j] = 0.f;
#pragma unroll
  for (int c = 0; c < 16; ++c) {
    float4 xv = xr[c];
    float h[4];
    h[0] = fmaxf(xv.x + b2[4*c+0], 0.f);
    h[1] = fmaxf(xv.y + b2[4*c+1], 0.f);
    h[2] = fmaxf(xv.z + b2[4*c+2], 0.f);
    h[3] = fmaxf(xv.w + b2[4*c+3], 0.f);
#pragma unroll
    for (int u = 0; u < 4; ++u)
#pragma unroll
      for (int j = 0; j < 8; ++j)
        acc[j] = fmaf(h[u], Wk[(4*c+u)*8 + j], acc[j]);
  }
  if (valid) {
    float* yr = out + (size_t)o_ * 8;
#pragma unroll
    for (int j = 0; j < 8; ++j) unsafeAtomicAdd(&yr[j], acc[j]);
  }
}

extern "C" void kernel_launch(void* const* d_in, const int* in_sizes, int n_in,
                              void* d_out, int out_size, void* d_ws, size_t ws_size,
                              hipStream_t stream) {
  const float* feats = (const float*)d_in[0];
  const float* W1 = (const float*)d_in[1];
  const float* b1 = (const float*)d_in[2];
  const float* W2 = (const float*)d_in[3];
  const float* b2 = (const float*)d_in[4];
  const float* W3 = (const float*)d_in[5];
  const float* b3 = (const float*)d_in[6];
  const int* m1i = (const int*)d_in[7];
  const int* m1o = (const int*)d_in[8];
  const int* m2i = (const int*)d_in[9];
  const int* m2o = (const int*)d_in[10];
  const int* m3i = (const int*)d_in[11];
  const int* m3o = (const int*)d_in[12];

  int n1 = in_sizes[0] / 8;    // 300000
  int L1 = in_sizes[7] / 27;
  int L2 = in_sizes[9] / 8;
  int L3 = in_sizes[11] / 27;
  int n2 = out_size / 8;       // output rows

  float* outp = (float*)d_out;
  float* y1 = (float*)d_ws;                    // n1 x 64 (no init needed: k=13 stores all rows)
  float* y2 = y1 + (size_t)n1 * 64;            // n2 x 64 (needs zero init)

  hipMemsetAsync(y2, 0, (size_t)n2 * 64 * sizeof(float), stream);

  int g1 = (n1 + TPB - 1) / TPB;
  k_conv1_center<<<g1, TPB, 0, stream>>>(feats, W1, y1, n1);

  dim3 gr1((L1 + TPB - 1) / TPB, 26);
  k_conv1_rest<<<gr1, TPB, 0, stream>>>(feats, W1, m1i, m1o, y1, L1, n1);

  dim3 g2((L2 + TPB - 1) / TPB, 8);
  k_conv2<<<g2, TPB, 0, stream>>>(y1, b1, W2, m2i, m2o, y2, L2, n2);

  int g3 = (n2 + TPB - 1) / TPB;
  k_conv3_center<<<g3, TPB, 0, stream>>>(y2, b2, W3, b3, outp, n2);

  dim3 gr3((L3 + TPB - 1) / TPB, 26);
  k_conv3_rest<<<gr3, TPB, 0, stream>>>(y2, b2, W3, m3i, m3o, outp, L3, n2);
}

// Round 2
// 746.500 us; speedup vs baseline: 7.9789x; 7.9789x over previous
//
#include <hip/hip_runtime.h>

// 3-layer sparse conv, gather formulation (zero atomics).
// Maps inverted into dense tables tbl[k][out] = in_idx (-1 invalid) — each
// (out,k) pair is unique, so builds are plain stores. Each conv: lane = output
// row, acc in VGPRs, W wave-uniform (s_load + SGPR-operand fmac), one store
// per row. bias+relu fused into producer stores; invalid gathers hit a
// dedicated zero row (broadcast) so the FMA loop is unconditional.

#define TPB 256

__global__ void __launch_bounds__(TPB)
k_build(const int* __restrict__ mi, const int* __restrict__ mo,
        int* __restrict__ tbl, int L, int n_out) {
  int k = blockIdx.y;
  int p = blockIdx.x * TPB + threadIdx.x;
  if (p >= L) return;
  int out = mo[(size_t)k * L + p];
  bool valid = out < n_out;                 // pads point at dummy row n_out
  if (__ballot(valid) == 0ull) return;      // pads are a contiguous tail
  if (valid) tbl[(size_t)k * n_out + out] = mi[(size_t)k * L + p];
}

// conv1: 8 -> 64, 27 offsets, gathers from feats (no zero row available ->
// cndmask-zero the 8 inputs for invalid lanes). Stores h1 = relu(acc + b1).
__global__ void __launch_bounds__(TPB)
k_conv1(const float* __restrict__ x, const float* __restrict__ W1,
        const float* __restrict__ b1, const int* __restrict__ t1,
        float* __restrict__ h1, int n1) {
  int r = blockIdx.x * TPB + threadIdx.x;
  if (r >= n1) return;
  float acc[64];
#pragma unroll
  for (int j = 0; j < 64; ++j) acc[j] = 0.f;
#pragma unroll 1
  for (int k = 0; k < 27; ++k) {
    int idx = t1[(size_t)k * n1 + r];
    bool v = idx >= 0;
    if (__ballot(v) == 0ull) continue;      // whole-wave miss: skip offset
    const float4* xr = (const float4*)(x + (size_t)(v ? idx : 0) * 8);
    float4 a = xr[0], b = xr[1];
    if (!v) { a = make_float4(0.f,0.f,0.f,0.f); b = make_float4(0.f,0.f,0.f,0.f); }
    float xv[8] = {a.x, a.y, a.z, a.w, b.x, b.y, b.z, b.w};
    const float* __restrict__ Wk = W1 + (size_t)k * 512;   // (8,64)
#pragma unroll
    for (int i = 0; i < 8; ++i)
#pragma unroll
      for (int j = 0; j < 64; ++j)
        acc[j] = fmaf(xv[i], Wk[i * 64 + j], acc[j]);
  }
  float4* yr = (float4*)(h1 + (size_t)r * 64);
#pragma unroll
  for (int q = 0; q < 16; ++q) {
    float4 o;
    o.x = fmaxf(acc[4*q+0] + b1[4*q+0], 0.f);
    o.y = fmaxf(acc[4*q+1] + b1[4*q+1], 0.f);
    o.z = fmaxf(acc[4*q+2] + b1[4*q+2], 0.f);
    o.w = fmaxf(acc[4*q+3] + b1[4*q+3], 0.f);
    yr[q] = o;
  }
}

// conv2: 64 -> 64, 8 offsets; gathers h1 rows (zero row n1 for invalid).
// Stores h2 = relu(acc + b2).
__global__ void __launch_bounds__(TPB)
k_conv2(const float* __restrict__ h1, const float* __restrict__ W2,
        const float* __restrict__ b2, const int* __restrict__ t2,
        float* __restrict__ h2, int n1, int n2) {
  int r = blockIdx.x * TPB + threadIdx.x;
  if (r >= n2) return;
  float acc[64];
#pragma unroll
  for (int j = 0; j < 64; ++j) acc[j] = 0.f;
#pragma unroll 1
  for (int k = 0; k < 8; ++k) {
    int idx = t2[(size_t)k * n2 + r];
    if (__ballot(idx >= 0) == 0ull) continue;
    int row = idx >= 0 ? idx : n1;          // zero row
    const float4* xr = (const float4*)(h1 + (size_t)row * 64);
    const float* __restrict__ Wk = W2 + (size_t)k * 4096;  // (64,64)
#pragma unroll 4
    for (int c = 0; c < 16; ++c) {
      float4 xv = xr[c];
#pragma unroll
      for (int j = 0; j < 64; ++j) {
        acc[j] = fmaf(xv.x, Wk[(4*c+0)*64 + j], acc[j]);
        acc[j] = fmaf(xv.y, Wk[(4*c+1)*64 + j], acc[j]);
        acc[j] = fmaf(xv.z, Wk[(4*c+2)*64 + j], acc[j]);
        acc[j] = fmaf(xv.w, Wk[(4*c+3)*64 + j], acc[j]);
      }
    }
  }
  float4* yr = (float4*)(h2 + (size_t)r * 64);
#pragma unroll
  for (int q = 0; q < 16; ++q) {
    float4 o;
    o.x = fmaxf(acc[4*q+0] + b2[4*q+0], 0.f);
    o.y = fmaxf(acc[4*q+1] + b2[4*q+1], 0.f);
    o.z = fmaxf(acc[4*q+2] + b2[4*q+2], 0.f);
    o.w = fmaxf(acc[4*q+3] + b2[4*q+3], 0.f);
    yr[q] = o;
  }
}

// conv3: 64 -> 8, 27 offsets; gathers h2 rows (zero row n2 for invalid).
// acc init = b3; plain store to d_out.
__global__ void __launch_bounds__(TPB)
k_conv3(const float* __restrict__ h2, const float* __restrict__ W3,
        const float* __restrict__ b3, const int* __restrict__ t3,
        float* __restrict__ out, int n2) {
  int r = blockIdx.x * TPB + threadIdx.x;
  if (r >= n2) return;
  float acc[8];
#pragma unroll
  for (int j = 0; j < 8; ++j) acc[j] = b3[j];
#pragma unroll 1
  for (int k = 0; k < 27; ++k) {
    int idx = t3[(size_t)k * n2 + r];
    if (__ballot(idx >= 0) == 0ull) continue;
    int row = idx >= 0 ? idx : n2;          // zero row
    const float4* xr = (const float4*)(h2 + (size_t)row * 64);
    const float* __restrict__ Wk = W3 + (size_t)k * 512;   // (64,8)
#pragma unroll
    for (int c = 0; c < 16; ++c) {
      float4 xv = xr[c];
      float hv[4] = {xv.x, xv.y, xv.z, xv.w};
#pragma unroll
      for (int u = 0; u < 4; ++u)
#pragma unroll
        for (int j = 0; j < 8; ++j)
          acc[j] = fmaf(hv[u], Wk[(4*c+u)*8 + j], acc[j]);
    }
  }
  float4* o = (float4*)(out + (size_t)r * 8);
  o[0] = make_float4(acc[0], acc[1], acc[2], acc[3]);
  o[1] = make_float4(acc[4], acc[5], acc[6], acc[7]);
}

extern "C" void kernel_launch(void* const* d_in, const int* in_sizes, int n_in,
                              void* d_out, int out_size, void* d_ws, size_t ws_size,
                              hipStream_t stream) {
  const float* feats = (const float*)d_in[0];
  const float* W1 = (const float*)d_in[1];
  const float* b1 = (const float*)d_in[2];
  const float* W2 = (const float*)d_in[3];
  const float* b2 = (const float*)d_in[4];
  const float* W3 = (const float*)d_in[5];
  const float* b3 = (const float*)d_in[6];
  const int* m1i = (const int*)d_in[7];
  const int* m1o = (const int*)d_in[8];
  const int* m2i = (const int*)d_in[9];
  const int* m2o = (const int*)d_in[10];
  const int* m3i = (const int*)d_in[11];
  const int* m3o = (const int*)d_in[12];

  int n1 = in_sizes[0] / 8;
  int L1 = in_sizes[7] / 27;
  int L2 = in_sizes[9] / 8;
  int L3 = in_sizes[11] / 27;
  int n2 = out_size / 8;

  // Workspace layout (t1 aliases the y2 region: t1 dead before conv2 writes y2)
  char* ws = (char*)d_ws;
  size_t y1_bytes = (size_t)(n1 + 1) * 64 * sizeof(float);
  size_t y2_bytes = (size_t)(n2 + 1) * 64 * sizeof(float);
  size_t t1_bytes = (size_t)27 * n1 * sizeof(int);
  size_t reg1_bytes = y2_bytes > t1_bytes ? y2_bytes : t1_bytes;
  float* y1 = (float*)ws;                              // h1: (n1+1) x 64
  float* y2 = (float*)(ws + y1_bytes);                 // h2: (n2+1) x 64
  int* t1 = (int*)(ws + y1_bytes);                     // alias (27 x n1)
  int* t2 = (int*)(ws + y1_bytes + reg1_bytes);        // 8 x n2
  int* t3 = (int*)(ws + y1_bytes + reg1_bytes + (size_t)8 * n2 * sizeof(int));

  // invalid = -1
  hipMemsetAsync(t1, 0xFF, t1_bytes, stream);
  hipMemsetAsync(t2, 0xFF, (size_t)8 * n2 * sizeof(int), stream);
  hipMemsetAsync(t3, 0xFF, (size_t)27 * n2 * sizeof(int), stream);

  k_build<<<dim3((L1 + TPB - 1) / TPB, 27), TPB, 0, stream>>>(m1i, m1o, t1, L1, n1);
  k_build<<<dim3((L2 + TPB - 1) / TPB, 8), TPB, 0, stream>>>(m2i, m2o, t2, L2, n2);
  k_build<<<dim3((L3 + TPB - 1) / TPB, 27), TPB, 0, stream>>>(m3i, m3o, t3, L3, n2);

  k_conv1<<<(n1 + TPB - 1) / TPB, TPB, 0, stream>>>(feats, W1, b1, t1, y1, n1);

  // zero rows for invalid gathers (y2's row is inside the t1 alias region's
  // buffer, so write it only after conv1 has consumed t1)
  hipMemsetAsync(y1 + (size_t)n1 * 64, 0, 64 * sizeof(float), stream);
  hipMemsetAsync(y2 + (size_t)n2 * 64, 0, 64 * sizeof(float), stream);

  k_conv2<<<(n2 + TPB - 1) / TPB, TPB, 0, stream>>>(y1, W2, b2, t2, y2, n1, n2);
  k_conv3<<<(n2 + TPB - 1) / TPB, TPB, 0, stream>>>(y2, W3, b3, t3, (float*)d_out, n2);
}